// Round 8
// baseline (12.067 us; speedup 1.0000x reference)
//
#include <hip/hip_runtime.h>
#include <math.h>

#define HN   512
#define N2M  32
#define LVAL 8192
#define TPB  512
#define STR  136   // f16 per LDS row (128 data + 8 pad)
#define STRD 68    // dword row stride

typedef _Float16 f16x8 __attribute__((ext_vector_type(8)));
typedef __fp16   pk16x2 __attribute__((ext_vector_type(2)));
typedef float    f32x4 __attribute__((ext_vector_type(4)));

// Split (x,y) into packed f16 hi + f16 lo residual via v_cvt_pkrtz.
__device__ __forceinline__ void split_store_pk(unsigned* dhi, unsigned* dlo,
                                               float x, float y) {
    const pk16x2 hi = __builtin_amdgcn_cvt_pkrtz(x, y);
    const float rx = x - (float)hi.x;
    const float ry = y - (float)hi.y;
    const pk16x2 lo = __builtin_amdgcn_cvt_pkrtz(rx, ry);
    *dhi = __builtin_bit_cast(unsigned, hi);
    *dlo = __builtin_bit_cast(unsigned, lo);
}

// One block per head h. l = 64*m + j, m in 0..127 (U table), j in 0..63 (W).
// Per-mode params are computed REDUNDANTLY in every thread (16 threads per
// mode duplicate the work) — no serial stage-1 head, no param LDS, and only
// ONE barrier on the block critical path (table writes -> MFMA reads).
__global__ __launch_bounds__(TPB, 4) void s4d_mfma(
    const float* __restrict__ log_dt,
    const float* __restrict__ B_real,
    const float* __restrict__ B_imag,
    const float* __restrict__ Cmat,
    const float* __restrict__ A_real,
    const float* __restrict__ A_imag,
    float* __restrict__ out)
{
    __shared__ __align__(16) _Float16 shU[128 * STR];
    __shared__ __align__(16) _Float16 shW[64 * STR];

    const int h = blockIdx.x;
    const int t = threadIdx.x;
    const int n  = t >> 4;    // mode 0..31
    const int lg = t & 15;    // row group 0..15

    // ---- per-mode params, in-register ----
    const int idx = h * N2M + n;
    const float dt  = expf(log_dt[h]);
    const float Are = -expf(A_real[idx]) - 1e-6f;
    const float Aim = A_imag[idx];
    const float hdt = 0.5f * dt;
    const float dre  = 1.0f - hdt * Are + 1e-6f;
    const float dim_ = -hdt * Aim;
    const float nre = 1.0f + hdt * Are;
    const float nim = hdt * Aim;
    const float inv = 1.0f / (dre * dre + dim_ * dim_);
    const float zr = (nre * dre + nim * dim_) * inv;
    const float zi = (nim * dre - nre * dim_) * inv;
    const float br = B_real[idx], bi = B_imag[idx];
    const float tbr = dt * ((br * dre + bi * dim_) * inv);
    const float tbi = dt * ((bi * dre - br * dim_) * inv);
    const float Cv = Cmat[idx];
    const float c2r = 2.0f * Cv * tbr;
    const float c2i = 2.0f * Cv * tbi;
    const float r2  = zr * zr + zi * zi;
    const float xl2 = 0.5f * log2f(r2);                       // log2|z|
    const float phi = atan2f(zi, zr) * 0.15915494309189535f;  // revolutions
    const float ph  = __uint_as_float(__float_as_uint(phi) & 0xFFFFE000u);
    const float pl  = phi - ph;
    // z^16 (W row step)
    const float e16  = __builtin_amdgcn_exp2f(16.0f * xl2);
    const float rv16 = __builtin_amdgcn_fractf(
        fmaf(16.0f, pl, __builtin_amdgcn_fractf(16.0f * ph)));
    const float z16r = e16 * __builtin_amdgcn_cosf(rv16);
    const float z16i = e16 * __builtin_amdgcn_sinf(rv16);
    // z^1024 (U row step: 64*16)
    const float e1k  = __builtin_amdgcn_exp2f(1024.0f * xl2);
    const float rv1k = __builtin_amdgcn_fractf(
        fmaf(1024.0f, pl, __builtin_amdgcn_fractf(1024.0f * ph)));
    const float zkr = e1k * __builtin_amdgcn_cosf(rv1k);
    const float zki = e1k * __builtin_amdgcn_sinf(rv1k);

    // ---- Stage B1: W table, rows j = lg + 16s ----
    {
        const float jf  = (float)lg;
        const float e   = __builtin_amdgcn_exp2f(jf * xl2);
        const float rev = __builtin_amdgcn_fractf(
            fmaf(jf, pl, __builtin_amdgcn_fractf(jf * ph)));
        float wr = e * __builtin_amdgcn_cosf(rev);
        float wi = e * __builtin_amdgcn_sinf(rev);
        unsigned* dw = (unsigned*)shW;
#pragma unroll
        for (int s = 0; s < 4; ++s) {
            const int j = lg + 16 * s;
            split_store_pk(dw + j * STRD + n, dw + j * STRD + 32 + n, wr, -wi);
            const float nr = wr * z16r - wi * z16i;
            wi = fmaf(wr, z16i, wi * z16r);
            wr = nr;
        }
    }

    // ---- Stage B2: U table, rows m = lg + 16s ----
    {
        const float l0f = (float)(lg << 6);   // 64*lg, exact
        const float e   = __builtin_amdgcn_exp2f(l0f * xl2);
        const float rev = __builtin_amdgcn_fractf(
            fmaf(l0f, pl, __builtin_amdgcn_fractf(l0f * ph)));
        const float cs_ = __builtin_amdgcn_cosf(rev);
        const float sn_ = __builtin_amdgcn_sinf(rev);
        float ur = e * fmaf(c2r, cs_, -(c2i * sn_));
        float ui = e * fmaf(c2r, sn_, c2i * cs_);
        unsigned* du = (unsigned*)shU;
#pragma unroll
        for (int s = 0; s < 8; ++s) {
            const int m = lg + 16 * s;
            split_store_pk(du + m * STRD + n, du + m * STRD + 32 + n, ur, ui);
            const float nr = ur * zkr - ui * zki;
            ui = fmaf(ur, zki, ui * zkr);
            ur = nr;
        }
    }
    __syncthreads();

    // ---- Stage C: 8 waves, wave w owns m-tile [16w, 16w+16) as B-operand ----
    const int w = t >> 6, lane = t & 63, g = lane >> 4, r = lane & 15;
    const _Float16* ub = shU + (w * 16 + r) * STR + g * 8;
    const f16x8 B0 = *(const f16x8*)(ub);        // U_hi k 0-31
    const f16x8 B1 = *(const f16x8*)(ub + 32);   // U_hi k 32-63
    const f16x8 B2 = *(const f16x8*)(ub + 64);   // U_lo k 0-31
    const f16x8 B3 = *(const f16x8*)(ub + 96);   // U_lo k 32-63
    float* outp = out + (size_t)h * LVAL;
#pragma unroll
    for (int jt = 0; jt < 4; ++jt) {
        const _Float16* wa = shW + (jt * 16 + r) * STR + g * 8;
        const f16x8 A0 = *(const f16x8*)(wa);        // W_hi k 0-31
        const f16x8 A1 = *(const f16x8*)(wa + 32);   // W_hi k 32-63
        const f16x8 A2 = *(const f16x8*)(wa + 64);   // W_lo k 0-31
        const f16x8 A3 = *(const f16x8*)(wa + 96);   // W_lo k 32-63
        f32x4 acc = {0.f, 0.f, 0.f, 0.f};
        acc = __builtin_amdgcn_mfma_f32_16x16x32_f16(A0, B0, acc, 0, 0, 0);
        acc = __builtin_amdgcn_mfma_f32_16x16x32_f16(A1, B1, acc, 0, 0, 0);
        acc = __builtin_amdgcn_mfma_f32_16x16x32_f16(A2, B0, acc, 0, 0, 0);
        acc = __builtin_amdgcn_mfma_f32_16x16x32_f16(A3, B1, acc, 0, 0, 0);
        acc = __builtin_amdgcn_mfma_f32_16x16x32_f16(A0, B2, acc, 0, 0, 0);
        acc = __builtin_amdgcn_mfma_f32_16x16x32_f16(A1, B3, acc, 0, 0, 0);
        // l = 64*(16w + r) + 16*jt + 4g + rr -> 4 consecutive l per lane
        float4 v = make_float4(acc[0], acc[1], acc[2], acc[3]);
        *(float4*)(outp + 64 * (16 * w + r) + 16 * jt + 4 * g) = v;
    }
}

extern "C" void kernel_launch(void* const* d_in, const int* in_sizes, int n_in,
                              void* d_out, int out_size, void* d_ws, size_t ws_size,
                              hipStream_t stream)
{
    const float* log_dt = (const float*)d_in[0];
    const float* B_real = (const float*)d_in[1];
    const float* B_imag = (const float*)d_in[2];
    const float* Cmat   = (const float*)d_in[3];
    // d_in[4] = Kc (unused by reference)
    const float* A_real = (const float*)d_in[5];
    const float* A_imag = (const float*)d_in[6];
    // d_in[7] = L (fixed 8192)
    float* out = (float*)d_out;

    s4d_mfma<<<dim3(HN), dim3(TPB), 0, stream>>>(log_dt, B_real, B_imag, Cmat,
                                                 A_real, A_imag, out);
}

// Round 9
// 11.761 us; speedup vs baseline: 1.0260x; 1.0260x over previous
//
#include <hip/hip_runtime.h>
#include <math.h>

#define HN   512
#define N2M  32
#define LVAL 8192
#define TPB  256
#define STR  136   // f16 per LDS row (128 data + 8 pad)
#define STRD 68    // dword row stride

typedef _Float16 f16x8 __attribute__((ext_vector_type(8)));
typedef __fp16   pk16x2 __attribute__((ext_vector_type(2)));
typedef float    f32x4 __attribute__((ext_vector_type(4)));

// Split (x,y) into packed f16 hi + f16 lo residual via v_cvt_pkrtz.
__device__ __forceinline__ void split_store_pk(unsigned* dhi, unsigned* dlo,
                                               float x, float y) {
    const pk16x2 hi = __builtin_amdgcn_cvt_pkrtz(x, y);
    const float rx = x - (float)hi.x;
    const float ry = y - (float)hi.y;
    const pk16x2 lo = __builtin_amdgcn_cvt_pkrtz(rx, ry);
    *dhi = __builtin_bit_cast(unsigned, hi);
    *dlo = __builtin_bit_cast(unsigned, lo);
}

// Block = (m-half bx, head h): l = 64*m + j, m in [64bx, 64bx+64), j in 0..63.
// 1024 blocks x 256 threads -> 4 blocks/CU (LDS 34.8KB), 4-wave barriers —
// twice the independent blocks of the 512x512 version, to hide each block's
// serial chain (params -> tables -> barrier -> MFMA -> stores).
// Per-mode params computed redundantly per thread (proven free in R7).
__global__ __launch_bounds__(TPB, 4) void s4d_mfma(
    const float* __restrict__ log_dt,
    const float* __restrict__ B_real,
    const float* __restrict__ B_imag,
    const float* __restrict__ Cmat,
    const float* __restrict__ A_real,
    const float* __restrict__ A_imag,
    float* __restrict__ out)
{
    __shared__ __align__(16) _Float16 shU[64 * STR];
    __shared__ __align__(16) _Float16 shW[64 * STR];

    const int h  = blockIdx.y;
    const int bx = blockIdx.x;
    const int t  = threadIdx.x;
    const int n  = t >> 3;    // mode 0..31
    const int lg = t & 7;     // row group 0..7

    // ---- per-mode params, in-register (redundant x8 per mode) ----
    const int idx = h * N2M + n;
    const float dt  = expf(log_dt[h]);
    const float Are = -expf(A_real[idx]) - 1e-6f;
    const float Aim = A_imag[idx];
    const float hdt = 0.5f * dt;
    const float dre  = 1.0f - hdt * Are + 1e-6f;
    const float dim_ = -hdt * Aim;
    const float nre = 1.0f + hdt * Are;
    const float nim = hdt * Aim;
    const float inv = 1.0f / (dre * dre + dim_ * dim_);
    const float zr = (nre * dre + nim * dim_) * inv;
    const float zi = (nim * dre - nre * dim_) * inv;
    const float br = B_real[idx], bi = B_imag[idx];
    const float tbr = dt * ((br * dre + bi * dim_) * inv);
    const float tbi = dt * ((bi * dre - br * dim_) * inv);
    const float Cv = Cmat[idx];
    const float c2r = 2.0f * Cv * tbr;
    const float c2i = 2.0f * Cv * tbi;
    const float r2  = zr * zr + zi * zi;
    const float xl2 = 0.5f * log2f(r2);                       // log2|z|
    const float phi = atan2f(zi, zr) * 0.15915494309189535f;  // revolutions
    const float ph  = __uint_as_float(__float_as_uint(phi) & 0xFFFFE000u);
    const float pl  = phi - ph;
    // z^8 (W row step)
    const float e8  = __builtin_amdgcn_exp2f(8.0f * xl2);
    const float rv8 = __builtin_amdgcn_fractf(
        fmaf(8.0f, pl, __builtin_amdgcn_fractf(8.0f * ph)));
    const float z8r = e8 * __builtin_amdgcn_cosf(rv8);
    const float z8i = e8 * __builtin_amdgcn_sinf(rv8);
    // z^512 (U row step: 64*8)
    const float e5  = __builtin_amdgcn_exp2f(512.0f * xl2);
    const float rv5 = __builtin_amdgcn_fractf(
        fmaf(512.0f, pl, __builtin_amdgcn_fractf(512.0f * ph)));
    const float z5r = e5 * __builtin_amdgcn_cosf(rv5);
    const float z5i = e5 * __builtin_amdgcn_sinf(rv5);

    // ---- Stage B1: W table, rows j = lg + 8s ----
    {
        const float jf  = (float)lg;
        const float e   = __builtin_amdgcn_exp2f(jf * xl2);
        const float rev = __builtin_amdgcn_fractf(
            fmaf(jf, pl, __builtin_amdgcn_fractf(jf * ph)));
        float wr = e * __builtin_amdgcn_cosf(rev);
        float wi = e * __builtin_amdgcn_sinf(rev);
        unsigned* dw = (unsigned*)shW;
#pragma unroll
        for (int s = 0; s < 8; ++s) {
            const int j = lg + 8 * s;
            split_store_pk(dw + j * STRD + n, dw + j * STRD + 32 + n, wr, -wi);
            const float nr = wr * z8r - wi * z8i;
            wi = fmaf(wr, z8i, wi * z8r);
            wr = nr;
        }
    }

    // ---- Stage B2: U table, rows m_loc = lg + 8s; l0 = 4096*bx + 64*m_loc ----
    {
        const float l0f = (float)((bx << 12) + (lg << 6));  // exact in f32
        const float e   = __builtin_amdgcn_exp2f(l0f * xl2);
        const float rev = __builtin_amdgcn_fractf(
            fmaf(l0f, pl, __builtin_amdgcn_fractf(l0f * ph)));
        const float cs_ = __builtin_amdgcn_cosf(rev);
        const float sn_ = __builtin_amdgcn_sinf(rev);
        float ur = e * fmaf(c2r, cs_, -(c2i * sn_));
        float ui = e * fmaf(c2r, sn_, c2i * cs_);
        unsigned* du = (unsigned*)shU;
#pragma unroll
        for (int s = 0; s < 8; ++s) {
            const int m = lg + 8 * s;
            split_store_pk(du + m * STRD + n, du + m * STRD + 32 + n, ur, ui);
            const float nr = ur * z5r - ui * z5i;
            ui = fmaf(ur, z5i, ui * z5r);
            ur = nr;
        }
    }
    __syncthreads();

    // ---- Stage C: 4 waves, wave w owns m-tile [16w, 16w+16) as B-operand ----
    const int w = t >> 6, lane = t & 63, g = lane >> 4, r = lane & 15;
    const _Float16* ub = shU + (w * 16 + r) * STR + g * 8;
    const f16x8 B0 = *(const f16x8*)(ub);        // U_hi k 0-31
    const f16x8 B1 = *(const f16x8*)(ub + 32);   // U_hi k 32-63
    const f16x8 B2 = *(const f16x8*)(ub + 64);   // U_lo k 0-31
    const f16x8 B3 = *(const f16x8*)(ub + 96);   // U_lo k 32-63
    float* outp = out + (size_t)h * LVAL + (bx << 12);
#pragma unroll
    for (int jt = 0; jt < 4; ++jt) {
        const _Float16* wa = shW + (jt * 16 + r) * STR + g * 8;
        const f16x8 A0 = *(const f16x8*)(wa);        // W_hi k 0-31
        const f16x8 A1 = *(const f16x8*)(wa + 32);   // W_hi k 32-63
        const f16x8 A2 = *(const f16x8*)(wa + 64);   // W_lo k 0-31
        const f16x8 A3 = *(const f16x8*)(wa + 96);   // W_lo k 32-63
        f32x4 acc = {0.f, 0.f, 0.f, 0.f};
        acc = __builtin_amdgcn_mfma_f32_16x16x32_f16(A0, B0, acc, 0, 0, 0);
        acc = __builtin_amdgcn_mfma_f32_16x16x32_f16(A1, B1, acc, 0, 0, 0);
        acc = __builtin_amdgcn_mfma_f32_16x16x32_f16(A2, B0, acc, 0, 0, 0);
        acc = __builtin_amdgcn_mfma_f32_16x16x32_f16(A3, B1, acc, 0, 0, 0);
        acc = __builtin_amdgcn_mfma_f32_16x16x32_f16(A0, B2, acc, 0, 0, 0);
        acc = __builtin_amdgcn_mfma_f32_16x16x32_f16(A1, B3, acc, 0, 0, 0);
        // l = 4096*bx + 64*(16w + r) + 16*jt + 4g + rr -> 4 consecutive l/lane
        float4 v = make_float4(acc[0], acc[1], acc[2], acc[3]);
        *(float4*)(outp + 64 * (16 * w + r) + 16 * jt + 4 * g) = v;
    }
}

extern "C" void kernel_launch(void* const* d_in, const int* in_sizes, int n_in,
                              void* d_out, int out_size, void* d_ws, size_t ws_size,
                              hipStream_t stream)
{
    const float* log_dt = (const float*)d_in[0];
    const float* B_real = (const float*)d_in[1];
    const float* B_imag = (const float*)d_in[2];
    const float* Cmat   = (const float*)d_in[3];
    // d_in[4] = Kc (unused by reference)
    const float* A_real = (const float*)d_in[5];
    const float* A_imag = (const float*)d_in[6];
    // d_in[7] = L (fixed 8192)
    float* out = (float*)d_out;

    dim3 grid(2, HN);   // (m-half, head) = 1024 blocks x 256 threads
    s4d_mfma<<<grid, dim3(TPB), 0, stream>>>(log_dt, B_real, B_imag, Cmat,
                                             A_real, A_imag, out);
}